// Round 4
// baseline (427.699 us; speedup 1.0000x reference)
//
#include <hip/hip_runtime.h>

#define BB 8
#define TT 2048
#define DD 768
#define EE 2304
#define MM (BB * TT)
#define MHK_ 768
#define LOG2E 1.44269504088896340736f

typedef __attribute__((ext_vector_type(8))) _Float16 f16x8;
typedef __attribute__((ext_vector_type(4))) float f32x4;

typedef const __attribute__((address_space(1))) void* gp_t;
typedef __attribute__((address_space(3))) void* lp_t;

__device__ __forceinline__ float fast_exp2(float x) { return __builtin_amdgcn_exp2f(x); }

// ---------- fused prep: zero l + x->f16 cast + tiled coalesced w transposes ----------
__global__ __launch_bounds__(256)
void k_prep(const float* __restrict__ x, const float* __restrict__ w_qkv,
            const float* __restrict__ w_out, _Float16* __restrict__ xh,
            _Float16* __restrict__ w_qkvT, _Float16* __restrict__ w_outT,
            float* __restrict__ lbuf) {
  __shared__ float tile[32][33];
  int bid = blockIdx.x;
  if (bid < 16) {
    lbuf[bid * 1024 + threadIdx.x * 4 + 0] = 0.f;
    lbuf[bid * 1024 + threadIdx.x * 4 + 1] = 0.f;
    lbuf[bid * 1024 + threadIdx.x * 4 + 2] = 0.f;
    lbuf[bid * 1024 + threadIdx.x * 4 + 3] = 0.f;
    return;
  }
  if (bid < 16 + 6144) {
    int idx = (bid - 16) * 256 + threadIdx.x;  // 8 f32 -> 8 f16 per thread
    const float4* p = (const float4*)(x + idx * 8);
    float4 a = p[0], b = p[1];
    f16x8 o;
    o[0] = (_Float16)a.x; o[1] = (_Float16)a.y; o[2] = (_Float16)a.z; o[3] = (_Float16)a.w;
    o[4] = (_Float16)b.x; o[5] = (_Float16)b.y; o[6] = (_Float16)b.z; o[7] = (_Float16)b.w;
    *(f16x8*)(xh + idx * 8) = o;
    return;
  }
  const float* in;
  _Float16* out;
  int R, C, t;
  if (bid < 6160 + 1728) {
    t = bid - 6160; in = w_qkv; out = w_qkvT; R = DD; C = EE;   // tiles: 24 x 72
  } else {
    t = bid - 7888; in = w_out; out = w_outT; R = DD; C = DD;   // tiles: 24 x 24
  }
  const int tpr = C / 32;
  const int r0 = (t / tpr) * 32, c0 = (t - (t / tpr) * tpr) * 32;
  const int tx = threadIdx.x & 31, ty = threadIdx.x >> 5;
  for (int k = 0; k < 4; k++)
    tile[ty + k * 8][tx] = in[(size_t)(r0 + ty + k * 8) * C + c0 + tx];
  __syncthreads();
  for (int k = 0; k < 4; k++)
    out[(size_t)(c0 + ty + k * 8) * R + r0 + tx] = (_Float16)tile[tx][ty + k * 8];
}

// ---------- V columns of qkv -> Vt[b][d][t] ----------
__global__ __launch_bounds__(256)
void k_vt(const _Float16* __restrict__ qkv, _Float16* __restrict__ Vt) {
  __shared__ _Float16 tile[32][33];
  const int tx = threadIdx.x & 31;
  const int ty = threadIdx.x >> 5;
  const int t0 = blockIdx.x * 32;
  const int d0 = blockIdx.y * 32;
  const int b = blockIdx.z;
  for (int r = 0; r < 4; r++) {
    int t = t0 + ty + r * 8;
    tile[ty + r * 8][tx] = qkv[(size_t)(b * TT + t) * EE + 2 * MHK_ + d0 + tx];
  }
  __syncthreads();
  for (int r = 0; r < 4; r++) {
    int d = d0 + ty + r * 8;
    Vt[((size_t)b * DD + d) * TT + t0 + tx] = tile[tx][ty + r * 8];
  }
}

// ---------- 8-phase MFMA GEMM: C[M,N] = A[M,K] * Bt[N,K]^T ----------
// 256x256 tile, BK=64 split in two 32-wide K-halves, 512 thr = 8 waves (2m x 4n),
// per-wave out 128x64 (acc[8][4] f32x4). LDS: As/Bs[2 dbuf][2 khalf][256*32] f16
// = 128 KB, 1 block/CU; overlap comes from the per-phase interleave, not TLP.
// Per K-tile: 4 phases (kh,rq): each = {8 ds_read_b128 | stage 1 half-tile
// (2 glds) | barrier | lgkmcnt(0)+sched_barrier | setprio(1) 16 MFMA setprio(0)
// | [vmcnt(4) at phase 1,3] | barrier}.
// Derived waits (provable): stage order per tile t is A-kh0(t+1), B-kh0(t+1),
// A-kh1(t+1), B-kh1(t+1) (1 half/phase, 2 glds each). At end of phase 1 the
// in-flight set is {kh1(t), kh0(t+1)} = 8 loads -> vmcnt(4) guarantees kh1(t)
// landed before phase 2's reads. At end of phase 3 in-flight = {kh0(t+1),
// kh1(t+1)} -> vmcnt(4) guarantees kh0(t+1) before next tile's phase 0.
// Main loop NEVER drains vmcnt to 0 (T3+T4). WAR is safe: buf[b^1] half kh is
// rewritten only after the closing barrier of the phase pair that read it.
// Read swizzle: LDS[r][slot] holds k-chunk slot^((r>>1)&3); reads use
// quad^((l16>>1)&3) -> verified 0 bank conflicts (round-1 measurement).
template<bool OUT_F16, bool HAS_BIAS, bool QSCALE, bool EXP_LSUM, bool ROWSCALE>
__global__ __launch_bounds__(512)
void k_gemm8(const _Float16* __restrict__ A, const _Float16* __restrict__ Bt,
             const float* __restrict__ bias, void* __restrict__ Cv,
             float* __restrict__ lbuf,
             int lda, int ldb, int ldc, int Kd,
             long long strideA, long long strideB, long long strideC,
             int gx, int gyp, float qscale) {
  __shared__ __align__(16) _Float16 As[2][2][256 * 32];
  __shared__ __align__(16) _Float16 Bs[2][2][256 * 32];
  const int tid = threadIdx.x;
  const int lane = tid & 63;
  const int w = tid >> 6;        // 0..7
  const int wm = w >> 2;         // 0..1 -> rows wm*128
  const int wn = w & 3;          // 0..3 -> cols wn*64
  const int quad = lane >> 4;
  const int l16 = lane & 15;

  // XCD-aware decode
  const int bid = blockIdx.x;
  const int xcd = bid & 7;
  int local = bid >> 3;
  const int perz = gx * gyp;
  const int z = local / perz;
  local -= z * perz;
  const int lm = local / gx;
  const int nblk = local - lm * gx;
  const int m0 = (xcd * gyp + lm) * 256;
  const int n0 = nblk * 256;

  // staging: thread covers row tid>>2 (+128 for 2nd glds), k-chunk (tid&3)^((tid>>3)&3)
  const int srow = tid >> 2;
  const int scc = ((tid & 3) ^ ((tid >> 3) & 3)) * 8;
  const _Float16* Ab = A + (long long)z * strideA + (size_t)(m0 + srow) * lda + scc;
  const _Float16* Bb = Bt + (long long)z * strideB + (size_t)(n0 + srow) * ldb + scc;
  const size_t a128 = (size_t)128 * lda;
  const size_t b128 = (size_t)128 * ldb;
  const int l0 = w * 64 * 8;          // wave-uniform glds dest (f16 idx), rd=0
  const int l1 = (512 + w * 64) * 8;  // rd=1

  const int fsw = (quad ^ ((l16 >> 1) & 3)) * 8;  // fragment k-chunk slot

  f32x4 acc[8][4];
#pragma unroll
  for (int i = 0; i < 8; i++)
#pragma unroll
    for (int j = 0; j < 4; j++)
#pragma unroll
      for (int r = 0; r < 4; r++) acc[i][j][r] = 0.f;

#define STG_A(b, kh, t) do { \
    const size_t ko_ = (size_t)(t) * 64 + (size_t)(kh) * 32; \
    __builtin_amdgcn_global_load_lds((gp_t)(Ab + ko_), (lp_t)(&As[b][kh][l0]), 16, 0, 0); \
    __builtin_amdgcn_global_load_lds((gp_t)(Ab + ko_ + a128), (lp_t)(&As[b][kh][l1]), 16, 0, 0); \
  } while (0)
#define STG_B(b, kh, t) do { \
    const size_t ko_ = (size_t)(t) * 64 + (size_t)(kh) * 32; \
    __builtin_amdgcn_global_load_lds((gp_t)(Bb + ko_), (lp_t)(&Bs[b][kh][l0]), 16, 0, 0); \
    __builtin_amdgcn_global_load_lds((gp_t)(Bb + ko_ + b128), (lp_t)(&Bs[b][kh][l1]), 16, 0, 0); \
  } while (0)
#define VM4 asm volatile("s_waitcnt vmcnt(4)" ::: "memory")
#define VM0 asm volatile("s_waitcnt vmcnt(0)" ::: "memory")
#define NOPS ((void)0)

#define PH(bb, KH, RQ, STAGE, VMW) do { \
    const __attribute__((address_space(3))) _Float16* Ah_ = \
        (const __attribute__((address_space(3))) _Float16*)&As[bb][KH][0]; \
    const __attribute__((address_space(3))) _Float16* Bh_ = \
        (const __attribute__((address_space(3))) _Float16*)&Bs[bb][KH][0]; \
    f16x8 af_[4], bf_[4]; \
    _Pragma("unroll") \
    for (int i = 0; i < 4; i++) \
      af_[i] = *(const __attribute__((address_space(3))) f16x8*)&Ah_[(wm * 128 + RQ * 64 + i * 16 + l16) * 32 + fsw]; \
    _Pragma("unroll") \
    for (int j = 0; j < 4; j++) \
      bf_[j] = *(const __attribute__((address_space(3))) f16x8*)&Bh_[(wn * 64 + j * 16 + l16) * 32 + fsw]; \
    STAGE; \
    __builtin_amdgcn_s_barrier(); \
    asm volatile("s_waitcnt lgkmcnt(0)" ::: "memory"); \
    __builtin_amdgcn_sched_barrier(0); \
    __builtin_amdgcn_s_setprio(1); \
    _Pragma("unroll") \
    for (int i = 0; i < 4; i++) \
      _Pragma("unroll") \
      for (int j = 0; j < 4; j++) \
        acc[RQ * 4 + i][j] = __builtin_amdgcn_mfma_f32_16x16x32_f16(af_[i], bf_[j], acc[RQ * 4 + i][j], 0, 0, 0); \
    __builtin_amdgcn_s_setprio(0); \
    VMW; \
    __builtin_amdgcn_s_barrier(); \
  } while (0)

  const int nt = Kd >> 6;
  // prologue: tile 0, all 4 halves, into buf 0 (8 loads/thread)
  STG_A(0, 0, 0); STG_B(0, 0, 0); STG_A(0, 1, 0); STG_B(0, 1, 0);
  VM4;  // kh0(0) landed (kh1(0) may be in flight)
  __builtin_amdgcn_s_barrier();

  for (int t = 0; t < nt - 1; ++t) {
    const int b = t & 1, bn = b ^ 1;
    PH(b, 0, 0, STG_A(bn, 0, t + 1), NOPS);
    PH(b, 0, 1, STG_B(bn, 0, t + 1), VM4);   // ensures kh1(t) before phase 2 reads
    PH(b, 1, 0, STG_A(bn, 1, t + 1), NOPS);
    PH(b, 1, 1, STG_B(bn, 1, t + 1), VM4);   // ensures kh0(t+1) before next tile
  }
  {
    const int b = (nt - 1) & 1;
    PH(b, 0, 0, NOPS, NOPS);
    PH(b, 0, 1, NOPS, VM0);                  // nothing staged: drain for kh1(last)
    PH(b, 1, 0, NOPS, NOPS);
    PH(b, 1, 1, NOPS, NOPS);
  }

  const long long cbase = (long long)z * strideC;
  const int colb = n0 + wn * 64;
  const int rowb = m0 + wm * 128;

  if (EXP_LSUM) {
    float psum[8][4];
#pragma unroll
    for (int i = 0; i < 8; i++)
#pragma unroll
      for (int r = 0; r < 4; r++) psum[i][r] = 0.f;
#pragma unroll
    for (int j = 0; j < 4; j++) {
      int col = colb + j * 16 + l16;
#pragma unroll
      for (int i = 0; i < 8; i++) {
        int row = rowb + i * 16 + quad * 4;
#pragma unroll
        for (int r = 0; r < 4; r++) {
          float p = fast_exp2(acc[i][j][r] - 24.f);
          psum[i][r] += p;
          ((_Float16*)Cv)[cbase + (size_t)(row + r) * ldc + col] = (_Float16)p;
        }
      }
    }
#pragma unroll
    for (int i = 0; i < 8; i++)
#pragma unroll
      for (int r = 0; r < 4; r++) {
        float v = psum[i][r];
        v += __shfl_xor(v, 1, 64);
        v += __shfl_xor(v, 2, 64);
        v += __shfl_xor(v, 4, 64);
        v += __shfl_xor(v, 8, 64);
        if (l16 == 0)
          atomicAdd(&lbuf[z * TT + rowb + i * 16 + quad * 4 + r], v);
      }
    return;
  }

  float invr[8][4];
  if (ROWSCALE) {
#pragma unroll
    for (int i = 0; i < 8; i++)
#pragma unroll
      for (int r = 0; r < 4; r++)
        invr[i][r] = 1.f / lbuf[z * TT + rowb + i * 16 + quad * 4 + r];
  }

#pragma unroll
  for (int j = 0; j < 4; j++) {
    int col = colb + j * 16 + l16;
    float bv = HAS_BIAS ? bias[col] : 0.f;
    float sc = 1.f;
    if (QSCALE && col < MHK_) sc = qscale;
#pragma unroll
    for (int i = 0; i < 8; i++) {
      int row = rowb + i * 16 + quad * 4;
#pragma unroll
      for (int r = 0; r < 4; r++) {
        float v = (acc[i][j][r] + bv) * sc;
        if (ROWSCALE) v = acc[i][j][r] * invr[i][r];
        if (OUT_F16)
          ((_Float16*)Cv)[cbase + (size_t)(row + r) * ldc + col] = (_Float16)v;
        else
          ((float*)Cv)[cbase + (size_t)(row + r) * ldc + col] = v;
      }
    }
  }
}

extern "C" void kernel_launch(void* const* d_in, const int* in_sizes, int n_in,
                              void* d_out, int out_size, void* d_ws, size_t ws_size,
                              hipStream_t stream) {
  const float* x = (const float*)d_in[0];
  const float* w_qkv = (const float*)d_in[1];
  const float* b_qkv = (const float*)d_in[2];
  const float* w_out = (const float*)d_in[3];
  const float* b_out = (const float*)d_in[4];

  _Float16* ws = (_Float16*)d_ws;
  _Float16* w_qkvT = ws;                         // [2304][768]
  _Float16* w_outT = w_qkvT + (size_t)EE * DD;   // [768][768]
  _Float16* qkv = w_outT + (size_t)DD * DD;      // [16384][2304]  (Q pre-scaled)
  _Float16* Vt = qkv + (size_t)MM * EE;          // [8][768][2048]
  _Float16* P = Vt + (size_t)BB * DD * TT;       // [8][2048][2048] = exp2(S-24)
  _Float16* ctx = P + (size_t)BB * TT * TT;      // [16384][768]
  float* lbuf = (float*)(ctx + (size_t)MM * DD); // [16384] row sums
  _Float16* xh = ctx + (size_t)MM * DD + MM * 2; // x-f16 after lbuf

  // 0. fused prep
  k_prep<<<8464, 256, 0, stream>>>(x, w_qkv, w_out, xh, w_qkvT, w_outT, lbuf);
  // 1. qkv projection (+bias, Q scaled into log2 domain)  [256x256, 576 blocks]
  k_gemm8<true, true, true, false, false><<<576, 512, 0, stream>>>(
      xh, w_qkvT, b_qkv, qkv, nullptr, DD, DD, EE, DD, 0, 0, 0, 9, 8, 0.125f * LOG2E);
  // 2. V -> Vt
  k_vt<<<dim3(TT / 32, DD / 32, BB), 256, 0, stream>>>(qkv, Vt);
  // 3. P = exp2(Q K^T - 24) + row sums (batched)  [256x256, 512 blocks]
  k_gemm8<true, false, false, true, false><<<512, 512, 0, stream>>>(
      qkv, qkv + MHK_, nullptr, P, lbuf, EE, EE, TT, DD,
      (long long)TT * EE, (long long)TT * EE, (long long)TT * TT, 8, 1, 1.f);
  // 4. ctx = (P V) / l (batched)  [256x256, 192 blocks]
  k_gemm8<true, false, false, false, true><<<192, 512, 0, stream>>>(
      P, Vt, nullptr, ctx, lbuf, TT, TT, DD, TT,
      (long long)TT * TT, (long long)DD * TT, (long long)TT * DD, 3, 1, 1.f);
  // 5. out = ctx w_out + b_out (fp32)  [256x256, 192 blocks]
  k_gemm8<false, true, false, false, false><<<192, 512, 0, stream>>>(
      ctx, w_outT, b_out, d_out, nullptr, DD, DD, DD, DD, 0, 0, 0, 3, 8, 1.f);
}

// Round 5
// 406.874 us; speedup vs baseline: 1.0512x; 1.0512x over previous
//
#include <hip/hip_runtime.h>

#define BB 8
#define TT 2048
#define DD 768
#define EE 2304
#define MM (BB * TT)
#define MHK_ 768
#define LOG2E 1.44269504088896340736f

typedef __attribute__((ext_vector_type(8))) _Float16 f16x8;
typedef __attribute__((ext_vector_type(4))) float f32x4;

typedef const __attribute__((address_space(1))) void* gp_t;
typedef __attribute__((address_space(3))) void* lp_t;

__device__ __forceinline__ float fast_exp2(float x) { return __builtin_amdgcn_exp2f(x); }

// ---------- fused prep: zero l + x->f16 cast + tiled coalesced w transposes ----------
__global__ __launch_bounds__(256)
void k_prep(const float* __restrict__ x, const float* __restrict__ w_qkv,
            const float* __restrict__ w_out, _Float16* __restrict__ xh,
            _Float16* __restrict__ w_qkvT, _Float16* __restrict__ w_outT,
            float* __restrict__ lbuf) {
  __shared__ float tile[32][33];
  int bid = blockIdx.x;
  if (bid < 16) {
    lbuf[bid * 1024 + threadIdx.x * 4 + 0] = 0.f;
    lbuf[bid * 1024 + threadIdx.x * 4 + 1] = 0.f;
    lbuf[bid * 1024 + threadIdx.x * 4 + 2] = 0.f;
    lbuf[bid * 1024 + threadIdx.x * 4 + 3] = 0.f;
    return;
  }
  if (bid < 16 + 6144) {
    int idx = (bid - 16) * 256 + threadIdx.x;  // 8 f32 -> 8 f16 per thread
    const float4* p = (const float4*)(x + idx * 8);
    float4 a = p[0], b = p[1];
    f16x8 o;
    o[0] = (_Float16)a.x; o[1] = (_Float16)a.y; o[2] = (_Float16)a.z; o[3] = (_Float16)a.w;
    o[4] = (_Float16)b.x; o[5] = (_Float16)b.y; o[6] = (_Float16)b.z; o[7] = (_Float16)b.w;
    *(f16x8*)(xh + idx * 8) = o;
    return;
  }
  const float* in;
  _Float16* out;
  int R, C, t;
  if (bid < 6160 + 1728) {
    t = bid - 6160; in = w_qkv; out = w_qkvT; R = DD; C = EE;   // tiles: 24 x 72
  } else {
    t = bid - 7888; in = w_out; out = w_outT; R = DD; C = DD;   // tiles: 24 x 24
  }
  const int tpr = C / 32;
  const int r0 = (t / tpr) * 32, c0 = (t - (t / tpr) * tpr) * 32;
  const int tx = threadIdx.x & 31, ty = threadIdx.x >> 5;
  for (int k = 0; k < 4; k++)
    tile[ty + k * 8][tx] = in[(size_t)(r0 + ty + k * 8) * C + c0 + tx];
  __syncthreads();
  for (int k = 0; k < 4; k++)
    out[(size_t)(c0 + ty + k * 8) * R + r0 + tx] = (_Float16)tile[tx][ty + k * 8];
}

// ---------- V columns of qkv -> Vt[b][d][t] ----------
__global__ __launch_bounds__(256)
void k_vt(const _Float16* __restrict__ qkv, _Float16* __restrict__ Vt) {
  __shared__ _Float16 tile[32][33];
  const int tx = threadIdx.x & 31;
  const int ty = threadIdx.x >> 5;
  const int t0 = blockIdx.x * 32;
  const int d0 = blockIdx.y * 32;
  const int b = blockIdx.z;
  for (int r = 0; r < 4; r++) {
    int t = t0 + ty + r * 8;
    tile[ty + r * 8][tx] = qkv[(size_t)(b * TT + t) * EE + 2 * MHK_ + d0 + tx];
  }
  __syncthreads();
  for (int r = 0; r < 4; r++) {
    int d = d0 + ty + r * 8;
    Vt[((size_t)b * DD + d) * TT + t0 + tx] = tile[tx][ty + r * 8];
  }
}

// ---------- MFMA GEMM: C[M,N] = A[M,K] * Bt[N,K]^T ----------
// 128x128 tile, BK=32, 4 waves. TRIPLE-buffered glds staging with COUNTED vmcnt
// (never drains in main loop):
//   prologue: stage tiles 0,1 (slots 0,1).
//   iter t: vmcnt(4) [retires tile t's 4 loads; tile t+1's stay IN FLIGHT across
//           the barrier] ; s_barrier ; sched_barrier(0) ; stage tile t+2 into
//           slot (t+2)%3 ; ds_read tile t from slot t%3 ; 16 MFMA.
//   Issue->wait distance = 2 iters (>L3/HBM latency) vs __syncthreads' implicit
//   vmcnt(0) that stalled ~300-500 cyc/iter (round-3 MfmaUtil 21%).
//   Final iter uses vmcnt(0): with only 4 loads left, vmcnt(4) would pass
//   vacuously without guaranteeing the last tile landed.
// WAR safety (1 barrier/iter): slot (t+2)%3 was last read in iter t-1; those
// ds_reads completed (lgkm) before their MFMA, which preceded each wave's
// arrival at the iter-t barrier. Per-wave vmcnt-then-barrier => all waves'
// tile-t loads globally complete at barrier release.
// Chunk swizzle (verified 0 bank conflicts in round 3):
//   LDS[row][slot] holds global k-chunk slot^((row>>1)&3); fragment reads use
//   quad^((l16>>1)&3); staging source pre-swizzled, glds dest stays linear.
// Epilogue modes: QKV (bias+Q log2-scale), S (P=exp2(s-24)+atomic row sums),
// PV (row scale 1/l), OUT (bias, f32).
template<bool OUT_F16, bool HAS_BIAS, bool QSCALE, bool EXP_LSUM, bool ROWSCALE>
__global__ __launch_bounds__(256)
void k_gemm(const _Float16* __restrict__ A, const _Float16* __restrict__ Bt,
            const float* __restrict__ bias, void* __restrict__ Cv,
            float* __restrict__ lbuf,
            int lda, int ldb, int ldc, int Kd,
            long long strideA, long long strideB, long long strideC,
            int gx, int gyp, float qscale) {
  __shared__ __align__(16) _Float16 As[3][128 * 32];
  __shared__ __align__(16) _Float16 Bs[3][128 * 32];
  const int tid = threadIdx.x;
  const int lane = tid & 63;
  const int w = tid >> 6;
  const int quad = lane >> 4;
  const int l16 = lane & 15;

  // XCD-aware decode of flattened block id
  const int bid = blockIdx.x;
  const int xcd = bid & 7;
  int local = bid >> 3;
  const int perz = gx * gyp;
  const int z = local / perz;
  local -= z * perz;
  const int lm = local / gx;
  const int nblk = local - lm * gx;
  const int m0 = (xcd * gyp + lm) * 128;
  const int n0 = nblk * 128;

  const int wr = (w >> 1) * 64;   // wave row base in tile
  const int wc = (w & 1) * 64;    // wave col base in tile

  // staging lane offsets: row = tid>>2, fetch chunk (tid&3)^((row>>1)&3)
  const int srow = tid >> 2;
  const int scc = ((tid & 3) ^ ((tid >> 3) & 3)) * 8;
  const _Float16* Abase = A + (long long)z * strideA + (size_t)(m0 + srow) * lda + scc;
  const _Float16* Bbase = Bt + (long long)z * strideB + (size_t)(n0 + srow) * ldb + scc;
  const size_t a64 = (size_t)64 * lda;
  const size_t b64 = (size_t)64 * ldb;
  const int wbase = (w * 16) * 32;  // wave-uniform LDS dest (lane*16B appended by HW)

  f32x4 acc[4][4];
  for (int i = 0; i < 4; i++)
    for (int j = 0; j < 4; j++)
      for (int r = 0; r < 4; r++) acc[i][j][r] = 0.f;

  // fragment k-chunk slot: quad ^ ((row>>1)&3), row bits>=4 don't matter
  const int fsw = (quad ^ ((l16 >> 1) & 3)) * 8;

#define STG(slot, t) do { \
    const size_t ko_ = (size_t)(t) * 32; \
    __builtin_amdgcn_global_load_lds((gp_t)(Abase + ko_), (lp_t)(&As[slot][wbase]), 16, 0, 0); \
    __builtin_amdgcn_global_load_lds((gp_t)(Abase + ko_ + a64), (lp_t)(&As[slot][wbase + 64 * 32]), 16, 0, 0); \
    __builtin_amdgcn_global_load_lds((gp_t)(Bbase + ko_), (lp_t)(&Bs[slot][wbase]), 16, 0, 0); \
    __builtin_amdgcn_global_load_lds((gp_t)(Bbase + ko_ + b64), (lp_t)(&Bs[slot][wbase + 64 * 32]), 16, 0, 0); \
  } while (0)

  const int niter = Kd >> 5;  // >= 24 for all call sites
  // prologue: tiles 0,1 -> slots 0,1 (8 loads/thread in flight)
  STG(0, 0);
  STG(1, 1);

  int rs = 0;   // read slot  = t % 3
  int wsl = 2;  // write slot = (t+2) % 3
  for (int it = 0; it < niter; it++) {
    if (it + 1 < niter)
      asm volatile("s_waitcnt vmcnt(4)" ::: "memory");   // tile t retired, t+1 in flight
    else
      asm volatile("s_waitcnt vmcnt(0)" ::: "memory");   // last tile must land
    __builtin_amdgcn_s_barrier();
    __builtin_amdgcn_sched_barrier(0);
    if (it + 2 < niter) STG(wsl, it + 2);
    f16x8 af[4], bf[4];
    for (int i = 0; i < 4; i++) af[i] = *(const f16x8*)&As[rs][(wr + i * 16 + l16) * 32 + fsw];
    for (int j = 0; j < 4; j++) bf[j] = *(const f16x8*)&Bs[rs][(wc + j * 16 + l16) * 32 + fsw];
    for (int i = 0; i < 4; i++)
      for (int j = 0; j < 4; j++)
        acc[i][j] = __builtin_amdgcn_mfma_f32_16x16x32_f16(af[i], bf[j], acc[i][j], 0, 0, 0);
    rs = (rs == 2) ? 0 : rs + 1;
    wsl = (wsl == 2) ? 0 : wsl + 1;
  }

  const long long cbase = (long long)z * strideC;

  if (EXP_LSUM) {
    // P = exp2(s - 24), f16; row sums accumulated to lbuf via device atomics
    float psum[4][4];
    for (int i = 0; i < 4; i++)
      for (int r = 0; r < 4; r++) psum[i][r] = 0.f;
    for (int j = 0; j < 4; j++) {
      int col = n0 + wc + j * 16 + l16;
      for (int i = 0; i < 4; i++) {
        int row = m0 + wr + i * 16 + quad * 4;
        for (int r = 0; r < 4; r++) {
          float p = fast_exp2(acc[i][j][r] - 24.f);
          psum[i][r] += p;
          ((_Float16*)Cv)[cbase + (size_t)(row + r) * ldc + col] = (_Float16)p;
        }
      }
    }
    for (int i = 0; i < 4; i++)
      for (int r = 0; r < 4; r++) {
        float v = psum[i][r];
        v += __shfl_xor(v, 1, 64);
        v += __shfl_xor(v, 2, 64);
        v += __shfl_xor(v, 4, 64);
        v += __shfl_xor(v, 8, 64);
        if (l16 == 0)
          atomicAdd(&lbuf[z * TT + m0 + wr + i * 16 + quad * 4 + r], v);
      }
    return;
  }

  float invr[4][4];
  if (ROWSCALE) {
    for (int i = 0; i < 4; i++)
      for (int r = 0; r < 4; r++)
        invr[i][r] = 1.f / lbuf[z * TT + m0 + wr + i * 16 + quad * 4 + r];
  }

  for (int j = 0; j < 4; j++) {
    int col = n0 + wc + j * 16 + l16;
    float bv = HAS_BIAS ? bias[col] : 0.f;
    float sc = 1.f;
    if (QSCALE && col < MHK_) sc = qscale;
    for (int i = 0; i < 4; i++) {
      int row = m0 + wr + i * 16 + quad * 4;
      for (int r = 0; r < 4; r++) {
        float v = (acc[i][j][r] + bv) * sc;
        if (ROWSCALE) v = acc[i][j][r] * invr[i][r];
        if (OUT_F16)
          ((_Float16*)Cv)[cbase + (size_t)(row + r) * ldc + col] = (_Float16)v;
        else
          ((float*)Cv)[cbase + (size_t)(row + r) * ldc + col] = v;
      }
    }
  }
}

extern "C" void kernel_launch(void* const* d_in, const int* in_sizes, int n_in,
                              void* d_out, int out_size, void* d_ws, size_t ws_size,
                              hipStream_t stream) {
  const float* x = (const float*)d_in[0];
  const float* w_qkv = (const float*)d_in[1];
  const float* b_qkv = (const float*)d_in[2];
  const float* w_out = (const float*)d_in[3];
  const float* b_out = (const float*)d_in[4];

  _Float16* ws = (_Float16*)d_ws;
  _Float16* w_qkvT = ws;                         // [2304][768]
  _Float16* w_outT = w_qkvT + (size_t)EE * DD;   // [768][768]
  _Float16* qkv = w_outT + (size_t)DD * DD;      // [16384][2304]  (Q pre-scaled)
  _Float16* Vt = qkv + (size_t)MM * EE;          // [8][768][2048]
  _Float16* P = Vt + (size_t)BB * DD * TT;       // [8][2048][2048] = exp2(S-24)
  _Float16* ctx = P + (size_t)BB * TT * TT;      // [16384][768]
  float* lbuf = (float*)(ctx + (size_t)MM * DD); // [16384] row sums
  _Float16* xh = ctx + (size_t)MM * DD + MM * 2; // x-f16 after lbuf

  // 0. fused prep (l zero + x cast + tiled weight transposes)
  k_prep<<<8464, 256, 0, stream>>>(x, w_qkv, w_out, xh, w_qkvT, w_outT, lbuf);
  // 1. qkv projection (+bias, Q scaled into log2 domain)  [128x128, 2304 blocks]
  k_gemm<true, true, true, false, false><<<2304, 256, 0, stream>>>(
      xh, w_qkvT, b_qkv, qkv, nullptr, DD, DD, EE, DD, 0, 0, 0, 18, 16, 0.125f * LOG2E);
  // 2. V -> Vt
  k_vt<<<dim3(TT / 32, DD / 32, BB), 256, 0, stream>>>(qkv, Vt);
  // 3. P = exp2(Q K^T - 24) + row sums (batched)  [128x128, 2048 blocks]
  k_gemm<true, false, false, true, false><<<2048, 256, 0, stream>>>(
      qkv, qkv + MHK_, nullptr, P, lbuf, EE, EE, TT, DD,
      (long long)TT * EE, (long long)TT * EE, (long long)TT * TT, 16, 2, 1.f);
  // 4. ctx = (P V) / l (batched)  [128x128, 768 blocks]
  k_gemm<true, false, false, false, true><<<768, 256, 0, stream>>>(
      P, Vt, nullptr, ctx, lbuf, TT, TT, DD, TT,
      (long long)TT * TT, (long long)DD * TT, (long long)TT * DD, 6, 2, 1.f);
  // 5. out = ctx w_out + b_out (fp32)  [128x128, 768 blocks]
  k_gemm<false, true, false, false, false><<<768, 256, 0, stream>>>(
      ctx, w_outT, b_out, d_out, nullptr, DD, DD, DD, DD, 0, 0, 0, 6, 16, 1.f);
}